// Round 1
// baseline (184.201 us; speedup 1.0000x reference)
//
#include <hip/hip_runtime.h>

#define KDET 100
#define NMS_THR 0.5f
#define IMGOFF 2666.0f   // 2 * 1333.0
#define CAP 1024         // max boxes per class (expected ~102, 90-sigma safe)
#define TILE 1024

// ---------------- init: zero cursors + output ----------------
__global__ void k_init(int* cursors, float* out, int C, int out_n) {
    int t = threadIdx.x;
    if (t < C) cursors[t] = 0;
    for (int u = t; u < out_n; u += blockDim.x) out[u] = 0.0f;
}

// ---------------- build: key gather + class-bucket scatter ----------------
__global__ void k_build(const float* __restrict__ iou_sc, const int* __restrict__ labels,
                        float* __restrict__ key, int* __restrict__ rank, int* __restrict__ keep,
                        int* cursors, int* clist, int n, int C) {
    int i = blockIdx.x * blockDim.x + threadIdx.x;
    if (i >= n) return;
    int c = labels[i];
    key[i]  = iou_sc[i * C + c];   // iou_scores[i, label[i]]
    rank[i] = 0;
    keep[i] = 0;
    int slot = atomicAdd(&cursors[c], 1);
    if (slot < CAP) clist[c * CAP + slot] = i;
}

// ---------------- per-class greedy NMS (exact decomposition) ----------------
__global__ __launch_bounds__(256) void k_nms(const float* __restrict__ boxes,
                                             const float* __restrict__ key,
                                             const int* __restrict__ cursors,
                                             const int* __restrict__ clist,
                                             int* __restrict__ keep) {
#pragma clang fp contract(off)
    __shared__ float sx1[CAP], sy1[CAP], sx2[CAP], sy2[CAP], skey[CAP];
    __shared__ int sidx[CAP], perm[CAP], skeep[CAP];
    int c = blockIdx.x;
    int cnt = cursors[c];
    if (cnt > CAP) cnt = CAP;
    if (cnt == 0) return;
    float off = (float)c * IMGOFF;   // exact: 2666*c integer < 2^24
    for (int t = threadIdx.x; t < cnt; t += blockDim.x) {
        int g = clist[c * CAP + t];
        // replicate reference: IoU computed on OFFSET boxes (fp32-quantized!)
        sx1[t] = boxes[g * 4 + 0] + off;
        sy1[t] = boxes[g * 4 + 1] + off;
        sx2[t] = boxes[g * 4 + 2] + off;
        sy2[t] = boxes[g * 4 + 3] + off;
        skey[t] = key[g];
        sidx[t] = g;
        skeep[t] = 1;
    }
    __syncthreads();
    // rank-sort by (key desc, orig idx asc) == stable argsort(-key)
    for (int t = threadIdx.x; t < cnt; t += blockDim.x) {
        float kt = skey[t]; int it = sidx[t];
        int r = 0;
        for (int j = 0; j < cnt; ++j) {
            float kj = skey[j];
            r += ((kj > kt) || (kj == kt && sidx[j] < it)) ? 1 : 0;
        }
        perm[r] = t;
    }
    __syncthreads();
    // greedy suppression in sorted order
    for (int p = 0; p < cnt - 1; ++p) {
        int e = perm[p];
        if (skeep[e]) {
            float ex1 = sx1[e], ey1 = sy1[e], ex2 = sx2[e], ey2 = sy2[e];
            float ea = (ex2 - ex1) * (ey2 - ey1);
            for (int q = p + 1 + (int)threadIdx.x; q < cnt; q += blockDim.x) {
                int f = perm[q];
                if (skeep[f]) {
                    // exact op order of reference _pairwise_iou
                    float ix1 = fmaxf(ex1, sx1[f]);
                    float iy1 = fmaxf(ey1, sy1[f]);
                    float ix2 = fminf(ex2, sx2[f]);
                    float iy2 = fminf(ey2, sy2[f]);
                    float iw = fmaxf(ix2 - ix1, 0.0f);
                    float ih = fmaxf(iy2 - iy1, 0.0f);
                    float inter = iw * ih;
                    float fa = (sx2[f] - sx1[f]) * (sy2[f] - sy1[f]);
                    float uni = (ea + fa) - inter;
                    float iou = inter / fmaxf(uni, 1e-9f);
                    if (iou > NMS_THR) skeep[f] = 0;
                }
            }
        }
        __syncthreads();
    }
    for (int t = threadIdx.x; t < cnt; t += blockDim.x)
        keep[sidx[t]] = skeep[t];
}

// ---------------- rank among kept by (score desc, key desc, idx asc) ----------------
// == lax.top_k order through the iou-sorted array (ties broken exactly)
__global__ __launch_bounds__(256) void k_rank(const float* __restrict__ scores,
                                              const float* __restrict__ key,
                                              const int* __restrict__ keep,
                                              int* __restrict__ rank, int n) {
    __shared__ float ss[TILE], kk[TILE];
    __shared__ int kp[TILE];
    int i = blockIdx.x * blockDim.x + threadIdx.x;
    int span = n / gridDim.y;
    int jbase = blockIdx.y * span;
    int jend = jbase + span;
    bool active = (i < n) && (keep[i] != 0);
    float si = active ? scores[i] : 0.0f;
    float ki = active ? key[i] : 0.0f;
    int cnt = 0;
    for (int t0 = jbase; t0 < jend; t0 += TILE) {
        __syncthreads();
        for (int u = threadIdx.x; u < TILE; u += blockDim.x) {
            int j = t0 + u;
            ss[u] = scores[j]; kk[u] = key[j]; kp[u] = keep[j];
        }
        __syncthreads();
        if (active) {
            for (int u = 0; u < TILE; ++u) {
                if (kp[u]) {
                    int j = t0 + u;
                    float sj = ss[u];
                    bool better = (sj > si) ||
                                  (sj == si && ((kk[u] > ki) || (kk[u] == ki && j < i)));
                    cnt += better ? 1 : 0;
                }
            }
        }
    }
    if (active && cnt) atomicAdd(&rank[i], cnt);
}

// ---------------- emit top-K ----------------
__global__ void k_emit(const float* __restrict__ boxes, const float* __restrict__ scores,
                       const int* __restrict__ labels, const int* __restrict__ keep,
                       const int* __restrict__ rank, float* __restrict__ out, int n) {
    int i = blockIdx.x * blockDim.x + threadIdx.x;
    if (i >= n) return;
    if (!keep[i]) return;
    int r = rank[i];
    if (r >= KDET) return;
    out[r * 4 + 0] = boxes[i * 4 + 0];   // raw (un-offset) boxes
    out[r * 4 + 1] = boxes[i * 4 + 1];
    out[r * 4 + 2] = boxes[i * 4 + 2];
    out[r * 4 + 3] = boxes[i * 4 + 3];
    out[KDET * 4 + r] = scores[i];
    out[KDET * 5 + r] = (float)labels[i];
    out[KDET * 6 + r] = 1.0f;
}

extern "C" void kernel_launch(void* const* d_in, const int* in_sizes, int n_in,
                              void* d_out, int out_size, void* d_ws, size_t ws_size,
                              hipStream_t stream) {
    const float* boxes  = (const float*)d_in[0];
    const float* scores = (const float*)d_in[1];
    const float* iou_sc = (const float*)d_in[2];
    const int*   labels = (const int*)d_in[3];
    float* out = (float*)d_out;
    int n = in_sizes[1];          // 8192
    int C = in_sizes[2] / n;      // 81

    char* ws = (char*)d_ws;
    int*   cursors = (int*)ws;                      // C ints
    float* key     = (float*)(ws + 1024);           // n floats
    int*   keep    = (int*)(ws + 1024 + 4 * (size_t)n);
    int*   rank    = (int*)(ws + 1024 + 8 * (size_t)n);
    int*   clist   = (int*)(ws + 1024 + 12 * (size_t)n);  // C*CAP ints (~330KB)

    hipLaunchKernelGGL(k_init, dim3(1), dim3(1024), 0, stream, cursors, out, C, out_size);
    hipLaunchKernelGGL(k_build, dim3((n + 255) / 256), dim3(256), 0, stream,
                       iou_sc, labels, key, rank, keep, cursors, clist, n, C);
    hipLaunchKernelGGL(k_nms, dim3(C), dim3(256), 0, stream, boxes, key, cursors, clist, keep);
    hipLaunchKernelGGL(k_rank, dim3((n + 255) / 256, 4), dim3(256), 0, stream,
                       scores, key, keep, rank, n);
    hipLaunchKernelGGL(k_emit, dim3((n + 255) / 256), dim3(256), 0, stream,
                       boxes, scores, labels, keep, rank, out, n);
}

// Round 2
// 126.804 us; speedup vs baseline: 1.4526x; 1.4526x over previous
//
#include <hip/hip_runtime.h>

#define KDET 100
#define NMS_THR 0.5f
#define IMGOFF 2666.0f    // 2 * 1333.0
#define CAP 256           // max boxes per class (expected ~102, sd ~10 -> 15 sigma)
#define NHIST 16384       // 14-bit score-bit buckets (shift 18)
#define HSHIFT 18
#define CAND 768          // candidate cap for final exact rank

// ---------------- init: zero cursors + hist + output ----------------
__global__ void k_init(int* cursors, int* hist, float* out, int C, int out_n) {
    int t = blockIdx.x * blockDim.x + threadIdx.x;
    if (t < NHIST) hist[t] = 0;
    if (t < out_n) out[t] = 0.0f;
    if (t < C) cursors[t] = 0;
}

// ---------------- build: key gather + class-bucket scatter ----------------
__global__ void k_build(const float* __restrict__ iou_sc, const int* __restrict__ labels,
                        float* __restrict__ key, int* __restrict__ keep,
                        int* cursors, int* clist, int n, int C) {
    int i = blockIdx.x * blockDim.x + threadIdx.x;
    if (i >= n) return;
    int c = labels[i];
    key[i]  = iou_sc[i * C + c];   // iou_scores[i, label[i]]
    keep[i] = 0;
    int slot = atomicAdd(&cursors[c], 1);
    if (slot < CAP) clist[c * CAP + slot] = i;
}

// ---------------- per-class bitmask NMS (exactly equivalent to greedy) ----------------
__global__ __launch_bounds__(256) void k_nms(const float* __restrict__ boxes,
                                             const float* __restrict__ scores,
                                             const float* __restrict__ key,
                                             const int* __restrict__ cursors,
                                             const int* __restrict__ clist,
                                             int* __restrict__ keep,
                                             int* __restrict__ hist) {
#pragma clang fp contract(off)
    __shared__ float sx1[CAP], sy1[CAP], sx2[CAP], sy2[CAP], skey[CAP], sarea[CAP];
    __shared__ int sidx[CAP], perm[CAP];
    __shared__ unsigned long long smask[CAP][CAP / 64];
    __shared__ unsigned long long srem[CAP / 64];
    int c = blockIdx.x;
    int cnt = cursors[c];
    if (cnt > CAP) cnt = CAP;
    if (cnt == 0) return;
    float off = (float)c * IMGOFF;   // exact: 2666*c integer < 2^24
    for (int t = threadIdx.x; t < cnt; t += blockDim.x) {
        int g = clist[c * CAP + t];
        // replicate reference: IoU computed on OFFSET boxes (fp32-quantized!)
        float x1 = boxes[g * 4 + 0] + off;
        float y1 = boxes[g * 4 + 1] + off;
        float x2 = boxes[g * 4 + 2] + off;
        float y2 = boxes[g * 4 + 3] + off;
        sx1[t] = x1; sy1[t] = y1; sx2[t] = x2; sy2[t] = y2;
        sarea[t] = (x2 - x1) * (y2 - y1);   // reference op order
        skey[t] = key[g];
        sidx[t] = g;
    }
    __syncthreads();
    // rank-sort by (key desc, orig idx asc) == stable argsort(-key)
    for (int t = threadIdx.x; t < cnt; t += blockDim.x) {
        float kt = skey[t]; int it = sidx[t];
        int r = 0;
        for (int j = 0; j < cnt; ++j) {
            float kj = skey[j];
            r += ((kj > kt) || (kj == kt && sidx[j] < it)) ? 1 : 0;
        }
        perm[r] = t;
    }
    __syncthreads();
    // parallel suppression-bit matrix in sorted coords: bit q of smask[p] = IoU>thr
    int NW = (cnt + 63) >> 6;
    for (int task = threadIdx.x; task < cnt * NW; task += blockDim.x) {
        int p = task / NW;
        int w = task - p * NW;
        int e = perm[p];
        float ex1 = sx1[e], ey1 = sy1[e], ex2 = sx2[e], ey2 = sy2[e], ea = sarea[e];
        unsigned long long word = 0ull;
        int qbase = w << 6;
        int qend = qbase + 64; if (qend > cnt) qend = cnt;
        for (int q = (qbase > p + 1 ? qbase : p + 1); q < qend; ++q) {
            int f = perm[q];
            // exact op order of reference _pairwise_iou
            float ix1 = fmaxf(ex1, sx1[f]);
            float iy1 = fmaxf(ey1, sy1[f]);
            float ix2 = fminf(ex2, sx2[f]);
            float iy2 = fminf(ey2, sy2[f]);
            float iw = fmaxf(ix2 - ix1, 0.0f);
            float ih = fmaxf(iy2 - iy1, 0.0f);
            float inter = iw * ih;
            float uni = (ea + sarea[f]) - inter;
            float iou = inter / fmaxf(uni, 1e-9f);
            if (iou > NMS_THR) word |= (1ull << (q - qbase));
        }
        smask[p][w] = word;
    }
    __syncthreads();
    // serial greedy mask scan (exact greedy equivalence), trivial work
    if (threadIdx.x == 0) {
        unsigned long long rem[CAP / 64] = {0ull};
        for (int p = 0; p < cnt; ++p) {
            if (!((rem[p >> 6] >> (p & 63)) & 1ull)) {
                for (int w = 0; w < NW; ++w) rem[w] |= smask[p][w];
            }
        }
        for (int w = 0; w < NW; ++w) srem[w] = rem[w];
    }
    __syncthreads();
    // write keep + fused score histogram of kept boxes
    for (int p = threadIdx.x; p < cnt; p += blockDim.x) {
        int kept = ((srem[p >> 6] >> (p & 63)) & 1ull) ? 0 : 1;
        int g = sidx[perm[p]];
        keep[g] = kept;
        if (kept) {
            unsigned b = __float_as_uint(scores[g]) >> HSHIFT;
            atomicAdd(&hist[b], 1);
        }
    }
}

// ---------------- select threshold bucket + gather candidates + exact rank + emit ----------------
__global__ __launch_bounds__(1024) void k_finale(const float* __restrict__ boxes,
                                                 const float* __restrict__ scores,
                                                 const int* __restrict__ labels,
                                                 const int* __restrict__ keep,
                                                 const float* __restrict__ key,
                                                 const int* __restrict__ hist,
                                                 float* __restrict__ out, int n) {
    __shared__ int csum[256];
    __shared__ int sT, sm;
    __shared__ float cs[CAND], ck[CAND];
    __shared__ int ci[CAND];
    int tid = threadIdx.x;
    // 256 chunks x 64 buckets suffix-select
    if (tid < 256) {
        int s = 0, base = tid * 64;
        for (int b = 0; b < 64; ++b) s += hist[base + b];
        csum[tid] = s;
    }
    if (tid == 0) sm = 0;
    __syncthreads();
    if (tid == 0) {
        int cum = 0, c;
        for (c = 255; c > 0; --c) {
            if (cum + csum[c] >= KDET) break;
            cum += csum[c];
        }
        int base = c * 64, b;
        for (b = 63; b > 0; --b) {
            cum += hist[base + b];
            if (cum >= KDET) break;
        }
        sT = base + b;   // top-K guaranteed within {bucket >= T}
    }
    __syncthreads();
    int T = sT;
    for (int i = tid; i < n; i += blockDim.x) {
        if (keep[i]) {
            int bk = (int)(__float_as_uint(scores[i]) >> HSHIFT);
            if (bk >= T) {
                int slot = atomicAdd(&sm, 1);
                if (slot < CAND) { cs[slot] = scores[i]; ck[slot] = key[i]; ci[slot] = i; }
            }
        }
    }
    __syncthreads();
    int m = sm; if (m > CAND) m = CAND;
    if (tid < m) {
        float si = cs[tid], ki = ck[tid];
        int ii = ci[tid];
        int r = 0;
        // exact rank by (score desc, key desc, idx asc) — lax.top_k tie order
        for (int j = 0; j < m; ++j) {
            float sj = cs[j];
            bool better = (sj > si) || (sj == si && ((ck[j] > ki) || (ck[j] == ki && ci[j] < ii)));
            r += better ? 1 : 0;
        }
        if (r < KDET) {
            out[r * 4 + 0] = boxes[ii * 4 + 0];   // raw (un-offset) boxes
            out[r * 4 + 1] = boxes[ii * 4 + 1];
            out[r * 4 + 2] = boxes[ii * 4 + 2];
            out[r * 4 + 3] = boxes[ii * 4 + 3];
            out[KDET * 4 + r] = si;
            out[KDET * 5 + r] = (float)labels[ii];
            out[KDET * 6 + r] = 1.0f;
        }
    }
}

extern "C" void kernel_launch(void* const* d_in, const int* in_sizes, int n_in,
                              void* d_out, int out_size, void* d_ws, size_t ws_size,
                              hipStream_t stream) {
    const float* boxes  = (const float*)d_in[0];
    const float* scores = (const float*)d_in[1];
    const float* iou_sc = (const float*)d_in[2];
    const int*   labels = (const int*)d_in[3];
    float* out = (float*)d_out;
    int n = in_sizes[1];          // 8192
    int C = in_sizes[2] / n;      // 81

    char* ws = (char*)d_ws;
    int*   cursors = (int*)ws;                               // C ints
    float* key     = (float*)(ws + 1024);                    // n floats
    int*   keep    = (int*)(ws + 1024 + 4 * (size_t)n);      // n ints
    int*   hist    = (int*)(ws + 1024 + 8 * (size_t)n);      // NHIST ints (64KB)
    int*   clist   = (int*)(ws + 1024 + 8 * (size_t)n + 4 * NHIST);  // C*CAP ints (~83KB)

    hipLaunchKernelGGL(k_init, dim3((NHIST + 255) / 256), dim3(256), 0, stream,
                       cursors, hist, out, C, out_size);
    hipLaunchKernelGGL(k_build, dim3((n + 255) / 256), dim3(256), 0, stream,
                       iou_sc, labels, key, keep, cursors, clist, n, C);
    hipLaunchKernelGGL(k_nms, dim3(C), dim3(256), 0, stream,
                       boxes, scores, key, cursors, clist, keep, hist);
    hipLaunchKernelGGL(k_finale, dim3(1), dim3(1024), 0, stream,
                       boxes, scores, labels, keep, key, hist, out, n);
}